// Round 2
// baseline (131.091 us; speedup 1.0000x reference)
//
#include <hip/hip_runtime.h>

// DigitCaps routing, multi-kernel version: heavy phases at grid = B*C = 4096
// blocks so all 256 CUs are busy (R1 kernel was 128 blocks -> half GPU idle,
// VALUBusy 12.5%, Occ 5.5%).
//
// Algebra (u_hat never materialized):
//   t0[b,c,o,q] = 0.1 * sum_hw u[b,c,hw,q]            (iter1 uniform softmax)
//   v = squash( s[o,p] = sum_{c,q} Wm[c,o,p,q] t[b,c,o,q] )
//   logits[b,n,o] = u . Wv_acc,  Wv_acc = Wm . (v1 + v2 + ...)  (linear in v)
//   t[b,c,o,q] = sum_hw softmax_o(logits) * u

#define CC 32
#define HWN 144
#define QQ 8
#define OO 10
#define PP 16
#define EE 80   // OO*QQ

// ---- K_pre: grid B*C=4096, block 64. t0 = 0.1 * channel-sum of x ----
__global__ __launch_bounds__(64)
void k_pre(const float* __restrict__ x, float* __restrict__ t) {
    const int blk = blockIdx.x;           // b*32 + c
    const int l   = threadIdx.x;
    const float* xc = x + (size_t)blk * (HWN * QQ);

    float us[QQ];
#pragma unroll
    for (int q = 0; q < QQ; ++q) us[q] = 0.f;
    for (int hw = l; hw < HWN; hw += 64) {
        const float4* p4 = (const float4*)(xc + hw * QQ);
        float4 a = p4[0], d = p4[1];
        us[0] += a.x; us[1] += a.y; us[2] += a.z; us[3] += a.w;
        us[4] += d.x; us[5] += d.y; us[6] += d.z; us[7] += d.w;
    }
#pragma unroll
    for (int m = 1; m <= 32; m <<= 1) {
#pragma unroll
        for (int q = 0; q < QQ; ++q) us[q] += __shfl_xor(us[q], m);
    }
    float* tb = t + (size_t)blk * EE;
    tb[l] = 0.1f * us[l & 7];
    if (l < 16) tb[64 + l] = 0.1f * us[l & 7];   // (64+l)&7 == l&7
}

// ---- K_v: grid B=128, block 192 (160 active). v = squash(Wm . t) ----
__global__ __launch_bounds__(192)
void k_v(const float* __restrict__ Wm, const float* __restrict__ t,
         float* __restrict__ v) {
    const int b = blockIdx.x, tid = threadIdx.x;
    if (tid >= OO * PP) return;
    const int o = tid >> 4, p = tid & 15;
    float s = 0.f;
    for (int cc = 0; cc < CC; ++cc) {
        const float4* w4 = (const float4*)(Wm + (((cc * OO + o) * PP + p) * QQ));
        const float4* t4 = (const float4*)(t + ((size_t)(b * CC + cc)) * EE + o * QQ);
        float4 w0 = w4[0], w1 = w4[1];
        float4 t0 = t4[0], t1 = t4[1];
        s += w0.x * t0.x + w0.y * t0.y + w0.z * t0.z + w0.w * t0.w
           + w1.x * t1.x + w1.y * t1.y + w1.z * t1.z + w1.w * t1.w;
    }
    float sn = s * s;
#pragma unroll
    for (int m = 1; m <= 8; m <<= 1) sn += __shfl_xor(sn, m);
    const float fac = sqrtf(sn) / (1.f + sn);
    v[b * (OO * PP) + tid] = s * fac;
}

// ---- K_t: grid 4096, block 64. logits/softmax/t for one (b,c) ----
__global__ __launch_bounds__(64)
void k_t(const float* __restrict__ x, const float* __restrict__ Wm,
         const float* __restrict__ v1, const float* __restrict__ v2, int nv,
         float* __restrict__ t) {
    const int blk = blockIdx.x;
    const int b = blk >> 5, c = blk & 31;
    const int l = threadIdx.x;

    __shared__ float v_s[OO * PP];
    __shared__ float wv_s[EE];
    __shared__ float tl_s[64][EE];   // 20 KB

    // vsum = v1 (+ v2)
    for (int e = l; e < OO * PP; e += 64) {
        float vv = v1[b * (OO * PP) + e];
        if (nv == 2) vv += v2[b * (OO * PP) + e];
        v_s[e] = vv;
    }
    __syncthreads();

    // wv[o,q] = sum_p Wm[c,o,p,q] * vsum[o,p]
    for (int e = l; e < EE; e += 64) {
        const int o = e >> 3, q = e & 7;
        const float* wp = Wm + ((size_t)(c * OO + o) * PP) * QQ + q;
        float acc = 0.f;
#pragma unroll
        for (int p = 0; p < PP; ++p) acc += wp[p * QQ] * v_s[o * PP + p];
        wv_s[e] = acc;
    }
    __syncthreads();

    float wv[EE];
#pragma unroll
    for (int e = 0; e < EE; ++e) wv[e] = wv_s[e];

    float tl[EE];
#pragma unroll
    for (int e = 0; e < EE; ++e) tl[e] = 0.f;

    const float* xc = x + (size_t)blk * (HWN * QQ);
    for (int hw = l; hw < HWN; hw += 64) {
        const float4* p4 = (const float4*)(xc + hw * QQ);
        float4 a = p4[0], d = p4[1];
        float u[QQ] = {a.x, a.y, a.z, a.w, d.x, d.y, d.z, d.w};
        float lg[OO];
        float mx = -1e30f;
#pragma unroll
        for (int o = 0; o < OO; ++o) {
            float s = 0.f;
#pragma unroll
            for (int q = 0; q < QQ; ++q) s += u[q] * wv[o * QQ + q];
            lg[o] = s;
            mx = fmaxf(mx, s);
        }
        float ssum = 0.f;
#pragma unroll
        for (int o = 0; o < OO; ++o) { lg[o] = __expf(lg[o] - mx); ssum += lg[o]; }
        const float inv = 1.f / ssum;
#pragma unroll
        for (int o = 0; o < OO; ++o) {
            const float cij = lg[o] * inv;
#pragma unroll
            for (int q = 0; q < QQ; ++q) tl[o * QQ + q] += cij * u[q];
        }
    }

    // lane-transpose reduction via LDS (staggered: 2 lanes/bank = free)
#pragma unroll
    for (int e = 0; e < EE; ++e) tl_s[l][e] = tl[e];
    __syncthreads();

    float acc0 = 0.f;
    for (int j = 0; j < 64; ++j) acc0 += tl_s[(j + l) & 63][l];
    float* tb = t + (size_t)blk * EE;
    tb[l] = acc0;
    if (l < 16) {
        float acc1 = 0.f;
        for (int j = 0; j < 64; ++j) acc1 += tl_s[(j + l) & 63][l + 64];
        tb[64 + l] = acc1;
    }
}

extern "C" void kernel_launch(void* const* d_in, const int* in_sizes, int n_in,
                              void* d_out, int out_size, void* d_ws, size_t ws_size,
                              hipStream_t stream) {
    const float* x  = (const float*)d_in[0];   // [128,32,12,12,8]
    const float* Wm = (const float*)d_in[1];   // [32,10,16,8]
    float* out = (float*)d_out;                // [128,10,16]

    float* t  = (float*)d_ws;                  // 4096*80 = 327680 f
    float* v1 = t + 4096 * EE;                 // 128*160 f
    float* v2 = v1 + 128 * OO * PP;            // 128*160 f  (1.44 MB total)

    k_pre<<<4096, 64, 0, stream>>>(x, t);
    k_v  <<<128, 192, 0, stream>>>(Wm, t, v1);
    k_t  <<<4096, 64, 0, stream>>>(x, Wm, v1, v1, 1, t);
    k_v  <<<128, 192, 0, stream>>>(Wm, t, v2);
    k_t  <<<4096, 64, 0, stream>>>(x, Wm, v1, v2, 2, t);
    k_v  <<<128, 192, 0, stream>>>(Wm, t, out);
}